// Round 15
// baseline (351.994 us; speedup 1.0000x reference)
//
#include <hip/hip_runtime.h>

// ---------------------------------------------------------------------------
// Fused Linear + SimPO loss on MI355X (gfx950)
// M = 4096 tokens, V = 32000, K = 2048
// GEMM R15 = R14 (int8 mfma_i32_16x16x64_i8, BM=BN=256, BK=64, 1024-thread
// block, 16 waves of 64x64, conflict-free swizzle, 1 block/CU, 4 waves/SIMD)
// with HALF the barriers: 2-tile super-iterations on a ping-pong of 32KB
// buffer PAIRS (4-ring, 128KB LDS). Per super-iter: stage both next-half
// tiles at start (drain distance ~730cy covers L2 latency), one VM0 + one
// barrier. Barriers per block: 32 -> 17.
// ---------------------------------------------------------------------------

typedef int i32x4 __attribute__((ext_vector_type(4)));

#define IGNORE_INDEX (-100)
#define BETA_ 0.1f
#define GAMMA_ 0.5f

#define M_TOK 4096
#define V_DIM 32000
#define K_DIM 2048
#define NVT 125          // V / 256
#define NMT 16           // M / 256
#define NS  16           // K / 128 (2-tile super-iterations)
#define BUFSZ 32768      // (256 + 256) * 64 * 1B per K-tile
#define HALF  65536      // 2 tiles
#define DESCALE 4.6493894e-5f   // (6/127) * (0.125/127)

__device__ inline char q8(float x, float inv_s) {
    int q = __float2int_rn(x * inv_s);
    q = q > 127 ? 127 : (q < -127 ? -127 : q);
    return (char)q;
}

// -------- fp32 -> int8 quantization, 4 elems/thread ------------------------
__global__ void __launch_bounds__(256) cvt_i8_kernel(const float* __restrict__ src,
                                                     char* __restrict__ dst,
                                                     float inv_s) {
    size_t i = ((size_t)blockIdx.x * 256 + threadIdx.x) * 4;
    float4 v = *reinterpret_cast<const float4*>(src + i);
    char4 o;
    o.x = q8(v.x, inv_s); o.y = q8(v.y, inv_s);
    o.z = q8(v.z, inv_s); o.w = q8(v.w, inv_s);
    *reinterpret_cast<char4*>(dst + i) = o;
}

// -------- exact fp32 target logit: one wave per token ----------------------
__global__ void __launch_bounds__(256) zt_kernel(const float* __restrict__ X,
                                                 const float* __restrict__ W,
                                                 const float* __restrict__ bias,
                                                 const int* __restrict__ target,
                                                 float* __restrict__ zt) {
    int token = blockIdx.x * 4 + (threadIdx.x >> 6);
    int lane = threadIdx.x & 63;
    int t = target[token];
    int tt = (t < 0) ? 0 : t;
    const float4* xr = reinterpret_cast<const float4*>(X + (size_t)token * K_DIM);
    const float4* wr = reinterpret_cast<const float4*>(W + (size_t)tt * K_DIM);
    float s = 0.f;
    #pragma unroll
    for (int j = 0; j < 8; ++j) {
        float4 a = xr[lane + j * 64];
        float4 b = wr[lane + j * 64];
        s += a.x * b.x + a.y * b.y + a.z * b.z + a.w * b.w;
    }
    #pragma unroll
    for (int m = 1; m < 64; m <<= 1) s += __shfl_xor(s, m, 64);
    if (lane == 0) zt[token] = s + bias[tt];
}

// -------- 256x256 INT8 GEMM, 2-tile super-iters, fused sum-exp epilogue ----
// LDS: two 64KB halves, each = 2 K-tiles. Per tile: A @0 ([256][64] i8,
// 16KB), B @16384 ([256][64] i8, 16KB). Row stride 64B = 4 x 16B slots.
// Swizzle: 16B slot c of row holds k-chunk (c ^ ((row>>1)&3)).
#define GLL(g, l) __builtin_amdgcn_global_load_lds( \
    (const __attribute__((address_space(1))) void*)(g), \
    (__attribute__((address_space(3))) void*)(l), 16, 0, 0)

__global__ void __launch_bounds__(1024, 4) gemm_lse_kernel(
    const char* __restrict__ Xq,             // [4096][2048] i8
    const char* __restrict__ Wq,             // [32000][2048] i8
    const float* __restrict__ bias,          // [32000]
    float* __restrict__ partials) {          // [NVT][4096] sum-exp partials
    __shared__ char lds[2 * HALF];           // 131072 B -> 1 block/CU

    const int tid = threadIdx.x;
    const int wid = tid >> 6;
    const int lane = tid & 63;
    const int r = lane & 15, g = lane >> 4;
    const int wm = wid >> 2, wn = wid & 3;   // 4x4 wave grid, 64x64 out each

    // bijective XCD-chunked swizzle: 2000 = 8 * 250, mt fastest inside chunk
    int nb = (blockIdx.x & 7) * 250 + (blockIdx.x >> 3);
    const int vt = nb >> 4;                  // 0..124
    const int mt = nb & 15;                  // 0..15

    // staging: thread covers row tid>>2, 16B chunk tid&3,
    // inverse-swizzled source chunk = (tid&3) ^ ((srow>>1)&3)
    const int srow = tid >> 2;               // 0..255
    const int sc = (((tid & 3) ^ ((srow >> 1) & 3)) << 4);
    const char* aS = Xq + (size_t)(mt * 256 + srow) * K_DIM + sc;
    const char* bS = Wq + (size_t)(vt * 256 + srow) * K_DIM + sc;

    char* sbase = lds + wid * 1024;          // wave-uniform staging base
    // fragment read offsets (b128): row*64 + swizzled 16B slot
    // slot = g ^ ((r>>1)&3)  (row-block offsets are 16-multiples)
    const int swz = (g ^ ((r >> 1) & 3)) << 4;
    const int vA = (wm * 64 + r) * 64 + swz;
    const int vB = 16384 + (wn * 64 + r) * 64 + swz;

    i32x4 acc[4][4] = {};
    i32x4 af[4], bf[4];

#define BARX do { \
    asm volatile("" ::: "memory"); \
    __builtin_amdgcn_s_barrier(); \
    asm volatile("" ::: "memory"); \
} while (0)

#define VM0 asm volatile("s_waitcnt vmcnt(0)" ::: "memory")

// stage one K-tile into buffer offset bofs, advance pointers by 64 k-bytes
#define STAGE(bofs) do { \
    GLL(aS, sbase + (bofs)); \
    GLL(bS, sbase + (bofs) + 16384); \
    aS += 64; bS += 64; \
} while (0)

#define RDALL(bofs) do { \
    _Pragma("unroll") \
    for (int n2 = 0; n2 < 4; ++n2) \
        bf[n2] = *(const i32x4*)(lds + (bofs) + vB + n2 * 1024); \
    _Pragma("unroll") \
    for (int m2 = 0; m2 < 4; ++m2) \
        af[m2] = *(const i32x4*)(lds + (bofs) + vA + m2 * 1024); \
} while (0)

#define MFMA16() do { \
    __builtin_amdgcn_s_setprio(1); \
    _Pragma("unroll") \
    for (int m2 = 0; m2 < 4; ++m2) { \
        _Pragma("unroll") \
        for (int n2 = 0; n2 < 4; ++n2) \
            acc[m2][n2] = __builtin_amdgcn_mfma_i32_16x16x64_i8( \
                af[m2], bf[n2], acc[m2][n2], 0, 0, 0); \
    } \
    __builtin_amdgcn_s_setprio(0); \
} while (0)

    // ---- prologue: stage tiles 0,1 into half0; drain; publish -------------
    STAGE(0);
    STAGE(BUFSZ);
    VM0;
    BARX;

    int pb = 0;
    #pragma unroll 1
    for (int s = 0; s < NS - 1; ++s) {
        // stage next-half tiles 2s+2, 2s+3 at iter start: their slots held
        // tiles 2s-2, 2s-1, read last super-iter and barrier-protected.
        // Drain distance to VM0 ~= 2 x (reads + 16 MFMA) ~ 730 cy.
        STAGE(pb ^ HALF);
        STAGE((pb ^ HALF) + BUFSZ);
        RDALL(pb);
        MFMA16();
        RDALL(pb + BUFSZ);
        MFMA16();
        VM0;             // own 4 GLLs (tiles 2s+2, 2s+3) complete
        BARX;            // publish to all waves
        pb ^= HALF;
    }
    // s = 15: tiles 30,31 ready (drained + barrier at end of s=14); no stage
    RDALL(pb);
    MFMA16();
    RDALL(pb + BUFSZ);
    MFMA16();

    // ---- epilogue: descale + bias + exp + row-sum over 256 cols ----------
    // C layout (16x16): col = lane&15, row = (lane>>4)*4 + reg
    float bb[4];
    #pragma unroll
    for (int nf = 0; nf < 4; ++nf)
        bb[nf] = bias[vt * 256 + wn * 64 + nf * 16 + r];

    __syncthreads();
    float* red = reinterpret_cast<float*>(lds);  // [4 wn][256 rows]
    #pragma unroll
    for (int mf = 0; mf < 4; ++mf) {
        #pragma unroll
        for (int i = 0; i < 4; ++i) {
            float s = 0.f;
            #pragma unroll
            for (int nf = 0; nf < 4; ++nf)
                s += __expf((float)acc[mf][nf][i] * DESCALE + bb[nf]);
            s += __shfl_xor(s, 1, 64);
            s += __shfl_xor(s, 2, 64);
            s += __shfl_xor(s, 4, 64);
            s += __shfl_xor(s, 8, 64);       // sum over 16 cols in group
            if (r == 0) red[wn * 256 + wm * 64 + mf * 16 + g * 4 + i] = s;
        }
    }
    __syncthreads();
    if (tid < 256) {
        float tot = red[tid] + red[256 + tid] + red[512 + tid] + red[768 + tid];
        partials[(size_t)vt * M_TOK + mt * 256 + tid] = tot;
    }
}

// -------- combine partials -> per-token logp -------------------------------
__global__ void __launch_bounds__(256) lse_kernel(const float* __restrict__ partials,
                                                  const float* __restrict__ zt,
                                                  float* __restrict__ logp) {
    int token = blockIdx.x * 256 + threadIdx.x;
    float s = 0.f;
    for (int v = 0; v < NVT; ++v) s += partials[(size_t)v * M_TOK + token];
    logp[token] = zt[token] - logf(s);
}

// -------- final SimPO scalar ----------------------------------------------
__global__ void __launch_bounds__(512) loss_kernel(const float* __restrict__ logp,
                                                   const int* __restrict__ target,
                                                   float* __restrict__ out) {
    __shared__ float ss[8], sc[8];
    int wid = threadIdx.x >> 6, lane = threadIdx.x & 63;
    float s = 0.f, cnt = 0.f;
    #pragma unroll
    for (int j = 0; j < 8; ++j) {
        int token = wid * 512 + lane + j * 64;
        if (target[token] != IGNORE_INDEX) { s += logp[token]; cnt += 1.f; }
    }
    #pragma unroll
    for (int m = 1; m < 64; m <<= 1) {
        s += __shfl_xor(s, m, 64);
        cnt += __shfl_xor(cnt, m, 64);
    }
    if (lane == 0) { ss[wid] = s; sc[wid] = cnt; }
    __syncthreads();
    if (threadIdx.x == 0) {
        float csum = 0.f, ccnt = 0.f;
        for (int b = 0; b < 4; ++b) { csum += ss[b]; ccnt += sc[b]; }
        float nll = -csum / ccnt;
        float pref = 0.f;
        for (int b = 0; b < 4; ++b) {
            float d = BETA_ * (ss[b] / sc[b] - ss[b + 4] / sc[b + 4]) - GAMMA_;
            float sp = (d > 0.f) ? log1pf(expf(-d)) : (-d + log1pf(expf(d)));
            pref += sp;
        }
        pref *= 0.25f;
        out[0] = nll + pref;
    }
}

// ---------------------------------------------------------------------------
extern "C" void kernel_launch(void* const* d_in, const int* in_sizes, int n_in,
                              void* d_out, int out_size, void* d_ws, size_t ws_size,
                              hipStream_t stream) {
    const float* W    = (const float*)d_in[0];
    const float* X    = (const float*)d_in[1];
    const int* target = (const int*)d_in[2];
    const float* bias = (const float*)d_in[3];
    float* out = (float*)d_out;
    char* ws = (char*)d_ws;

    // workspace layout (16B aligned), ~78 MB total
    char* Wq          = ws;                                        // 65,536,000 B
    char* Xq          = ws + 65536000;                             //  8,388,608 B
    float* partials   = (float*)(ws + 73924608);                   //  2,048,000 B
    float* zt         = (float*)(ws + 78020608);                   //     16,384 B
    float* logp       = (float*)(ws + 78036992);                   //     16,384 B

    cvt_i8_kernel<<<dim3(64000), 256, 0, stream>>>(W, Wq, 127.0f / 0.125f);
    cvt_i8_kernel<<<dim3(8192), 256, 0, stream>>>(X, Xq, 127.0f / 6.0f);
    zt_kernel<<<dim3(1024), 256, 0, stream>>>(X, W, bias, target, zt);
    gemm_lse_kernel<<<dim3(NMT * NVT), 1024, 0, stream>>>(Xq, Wq, bias, partials);
    lse_kernel<<<dim3(16), 256, 0, stream>>>(partials, zt, logp);
    loss_kernel<<<dim3(1), 512, 0, stream>>>(logp, target, out);
}

// Round 16
// 340.520 us; speedup vs baseline: 1.0337x; 1.0337x over previous
//
#include <hip/hip_runtime.h>

// ---------------------------------------------------------------------------
// Fused Linear + SimPO loss on MI355X (gfx950)
// M = 4096 tokens, V = 32000, K = 2048
// GEMM R16 = R14 (int8 mfma_i32_16x16x64_i8, BM=BN=256, BK=64, 1024-thread
// block, 16 waves of 64x64, tri-buffer ring, one barrier/K-tile, VM2 drains,
// conflict-free ((row>>1)&3) swizzle) with 3 micro-scheduling fixes:
// (1) earliest-dependency read order bf0,af0,bf1,af1,... -> first MFMA
//     waits on 2 reads, not 5; (2) STAGE issued after the first read pair
//     (GLL latency starts earlier, first MFMA undelayed); (3) setprio
//     dropped (m190: negative on non-phase-split GEMM structures).
// R15's super-iteration reverted (regressed: -7%).
// ---------------------------------------------------------------------------

typedef int i32x4 __attribute__((ext_vector_type(4)));

#define IGNORE_INDEX (-100)
#define BETA_ 0.1f
#define GAMMA_ 0.5f

#define M_TOK 4096
#define V_DIM 32000
#define K_DIM 2048
#define NVT 125          // V / 256
#define NMT 16           // M / 256
#define NT  32           // K / 64  (K-tiles)
#define BUFSZ 32768      // (256 + 256) * 64 * 1B
#define DESCALE 4.6493894e-5f   // (6/127) * (0.125/127)

__device__ inline char q8(float x, float inv_s) {
    int q = __float2int_rn(x * inv_s);
    q = q > 127 ? 127 : (q < -127 ? -127 : q);
    return (char)q;
}

// -------- fp32 -> int8 quantization, 4 elems/thread ------------------------
__global__ void __launch_bounds__(256) cvt_i8_kernel(const float* __restrict__ src,
                                                     char* __restrict__ dst,
                                                     float inv_s) {
    size_t i = ((size_t)blockIdx.x * 256 + threadIdx.x) * 4;
    float4 v = *reinterpret_cast<const float4*>(src + i);
    char4 o;
    o.x = q8(v.x, inv_s); o.y = q8(v.y, inv_s);
    o.z = q8(v.z, inv_s); o.w = q8(v.w, inv_s);
    *reinterpret_cast<char4*>(dst + i) = o;
}

// -------- exact fp32 target logit: one wave per token ----------------------
__global__ void __launch_bounds__(256) zt_kernel(const float* __restrict__ X,
                                                 const float* __restrict__ W,
                                                 const float* __restrict__ bias,
                                                 const int* __restrict__ target,
                                                 float* __restrict__ zt) {
    int token = blockIdx.x * 4 + (threadIdx.x >> 6);
    int lane = threadIdx.x & 63;
    int t = target[token];
    int tt = (t < 0) ? 0 : t;
    const float4* xr = reinterpret_cast<const float4*>(X + (size_t)token * K_DIM);
    const float4* wr = reinterpret_cast<const float4*>(W + (size_t)tt * K_DIM);
    float s = 0.f;
    #pragma unroll
    for (int j = 0; j < 8; ++j) {
        float4 a = xr[lane + j * 64];
        float4 b = wr[lane + j * 64];
        s += a.x * b.x + a.y * b.y + a.z * b.z + a.w * b.w;
    }
    #pragma unroll
    for (int m = 1; m < 64; m <<= 1) s += __shfl_xor(s, m, 64);
    if (lane == 0) zt[token] = s + bias[tt];
}

// -------- 256x256 tri-buffered INT8 GEMM with fused sum-exp epilogue -------
// LDS buffer (3-ring, stride 32768): A @0 ([256 rows][64 k] i8, 16KB),
// B @16384 ([256 rows][64 k] i8, 16KB). Row stride 64B = 4 x 16B slots.
// Swizzle: 16B slot c of row holds k-chunk (c ^ ((row>>1)&3)).
#define GLL(g, l) __builtin_amdgcn_global_load_lds( \
    (const __attribute__((address_space(1))) void*)(g), \
    (__attribute__((address_space(3))) void*)(l), 16, 0, 0)

__global__ void __launch_bounds__(1024, 4) gemm_lse_kernel(
    const char* __restrict__ Xq,             // [4096][2048] i8
    const char* __restrict__ Wq,             // [32000][2048] i8
    const float* __restrict__ bias,          // [32000]
    float* __restrict__ partials) {          // [NVT][4096] sum-exp partials
    __shared__ char lds[3 * BUFSZ];          // 98304 B -> 1 block/CU, 16 waves

    const int tid = threadIdx.x;
    const int wid = tid >> 6;
    const int lane = tid & 63;
    const int r = lane & 15, g = lane >> 4;
    const int wm = wid >> 2, wn = wid & 3;   // 4x4 wave grid, 64x64 out each

    // bijective XCD-chunked swizzle: 2000 = 8 * 250, mt fastest inside chunk
    int nb = (blockIdx.x & 7) * 250 + (blockIdx.x >> 3);
    const int vt = nb >> 4;                  // 0..124
    const int mt = nb & 15;                  // 0..15

    // staging: thread covers row tid>>2, 16B chunk tid&3,
    // inverse-swizzled source chunk = (tid&3) ^ ((srow>>1)&3)
    const int srow = tid >> 2;               // 0..255
    const int sc = (((tid & 3) ^ ((srow >> 1) & 3)) << 4);
    const char* aS = Xq + (size_t)(mt * 256 + srow) * K_DIM + sc;
    const char* bS = Wq + (size_t)(vt * 256 + srow) * K_DIM + sc;

    char* sbase = lds + wid * 1024;          // wave-uniform staging base
    // fragment read offsets (b128): row*64 + swizzled 16B slot
    // slot = g ^ ((r>>1)&3)  (row-block offsets are 16-multiples)
    const int swz = (g ^ ((r >> 1) & 3)) << 4;
    const int vA = (wm * 64 + r) * 64 + swz;
    const int vB = 16384 + (wn * 64 + r) * 64 + swz;

    i32x4 acc[4][4] = {};
    i32x4 af[4], bf[4];

#define BARX do { \
    asm volatile("" ::: "memory"); \
    __builtin_amdgcn_s_barrier(); \
    asm volatile("" ::: "memory"); \
} while (0)

#define VM2 asm volatile("s_waitcnt vmcnt(2)" ::: "memory")
#define VM0 asm volatile("s_waitcnt vmcnt(0)" ::: "memory")

#define STAGE(bofs) do { \
    GLL(aS, sbase + (bofs)); \
    GLL(bS, sbase + (bofs) + 16384); \
    aS += 64; bS += 64; \
} while (0)

// read pair i: bf[i] then af[i] — earliest-dependency order
#define RD2(bofs, i) do { \
    bf[i] = *(const i32x4*)(lds + (bofs) + vB + (i) * 1024); \
    af[i] = *(const i32x4*)(lds + (bofs) + vA + (i) * 1024); \
} while (0)

#define MFMA16() do { \
    _Pragma("unroll") \
    for (int m2 = 0; m2 < 4; ++m2) { \
        _Pragma("unroll") \
        for (int n2 = 0; n2 < 4; ++n2) \
            acc[m2][n2] = __builtin_amdgcn_mfma_i32_16x16x64_i8( \
                af[m2], bf[n2], acc[m2][n2], 0, 0, 0); \
    } \
} while (0)

    // ---- prologue: stage tiles 0,1 into buffers 0,1; ensure t0 done -------
    STAGE(0);
    STAGE(BUFSZ);
    VM2;                 // 4 outstanding -> oldest 2 (tile 0) complete
    BARX;

    int cur = 0, nxt = BUFSZ, nx2 = 2 * BUFSZ;
    #pragma unroll 1
    for (int t = 0; t < NT - 2; ++t) {
        RD2(cur, 0);     // first MFMA depends only on these two reads
        STAGE(nx2);      // GLL latency starts here, hides under MFMA block
        RD2(cur, 1);
        RD2(cur, 2);
        RD2(cur, 3);
        MFMA16();
        VM2;             // tile t+1 GLLs complete before publishing barrier
        BARX;
        int tmp = cur; cur = nxt; nxt = nx2; nx2 = tmp;
    }
    // t = 30: no stage; drain everything (tile 31) before its reads
    RD2(cur, 0); RD2(cur, 1); RD2(cur, 2); RD2(cur, 3);
    MFMA16();
    VM0;
    BARX;
    // t = 31
    RD2(nxt, 0); RD2(nxt, 1); RD2(nxt, 2); RD2(nxt, 3);
    MFMA16();

    // ---- epilogue: descale + bias + exp + row-sum over 256 cols ----------
    // C layout (16x16): col = lane&15, row = (lane>>4)*4 + reg
    float bb[4];
    #pragma unroll
    for (int nf = 0; nf < 4; ++nf)
        bb[nf] = bias[vt * 256 + wn * 64 + nf * 16 + r];

    __syncthreads();
    float* red = reinterpret_cast<float*>(lds);  // [4 wn][256 rows]
    #pragma unroll
    for (int mf = 0; mf < 4; ++mf) {
        #pragma unroll
        for (int i = 0; i < 4; ++i) {
            float s = 0.f;
            #pragma unroll
            for (int nf = 0; nf < 4; ++nf)
                s += __expf((float)acc[mf][nf][i] * DESCALE + bb[nf]);
            s += __shfl_xor(s, 1, 64);
            s += __shfl_xor(s, 2, 64);
            s += __shfl_xor(s, 4, 64);
            s += __shfl_xor(s, 8, 64);       // sum over 16 cols in group
            if (r == 0) red[wn * 256 + wm * 64 + mf * 16 + g * 4 + i] = s;
        }
    }
    __syncthreads();
    if (tid < 256) {
        float tot = red[tid] + red[256 + tid] + red[512 + tid] + red[768 + tid];
        partials[(size_t)vt * M_TOK + mt * 256 + tid] = tot;
    }
}

// -------- combine partials -> per-token logp -------------------------------
__global__ void __launch_bounds__(256) lse_kernel(const float* __restrict__ partials,
                                                  const float* __restrict__ zt,
                                                  float* __restrict__ logp) {
    int token = blockIdx.x * 256 + threadIdx.x;
    float s = 0.f;
    for (int v = 0; v < NVT; ++v) s += partials[(size_t)v * M_TOK + token];
    logp[token] = zt[token] - logf(s);
}

// -------- final SimPO scalar ----------------------------------------------
__global__ void __launch_bounds__(512) loss_kernel(const float* __restrict__ logp,
                                                   const int* __restrict__ target,
                                                   float* __restrict__ out) {
    __shared__ float ss[8], sc[8];
    int wid = threadIdx.x >> 6, lane = threadIdx.x & 63;
    float s = 0.f, cnt = 0.f;
    #pragma unroll
    for (int j = 0; j < 8; ++j) {
        int token = wid * 512 + lane + j * 64;
        if (target[token] != IGNORE_INDEX) { s += logp[token]; cnt += 1.f; }
    }
    #pragma unroll
    for (int m = 1; m < 64; m <<= 1) {
        s += __shfl_xor(s, m, 64);
        cnt += __shfl_xor(cnt, m, 64);
    }
    if (lane == 0) { ss[wid] = s; sc[wid] = cnt; }
    __syncthreads();
    if (threadIdx.x == 0) {
        float csum = 0.f, ccnt = 0.f;
        for (int b = 0; b < 4; ++b) { csum += ss[b]; ccnt += sc[b]; }
        float nll = -csum / ccnt;
        float pref = 0.f;
        for (int b = 0; b < 4; ++b) {
            float d = BETA_ * (ss[b] / sc[b] - ss[b + 4] / sc[b + 4]) - GAMMA_;
            float sp = (d > 0.f) ? log1pf(expf(-d)) : (-d + log1pf(expf(d)));
            pref += sp;
        }
        pref *= 0.25f;
        out[0] = nll + pref;
    }
}

// ---------------------------------------------------------------------------
extern "C" void kernel_launch(void* const* d_in, const int* in_sizes, int n_in,
                              void* d_out, int out_size, void* d_ws, size_t ws_size,
                              hipStream_t stream) {
    const float* W    = (const float*)d_in[0];
    const float* X    = (const float*)d_in[1];
    const int* target = (const int*)d_in[2];
    const float* bias = (const float*)d_in[3];
    float* out = (float*)d_out;
    char* ws = (char*)d_ws;

    // workspace layout (16B aligned), ~78 MB total
    char* Wq          = ws;                                        // 65,536,000 B
    char* Xq          = ws + 65536000;                             //  8,388,608 B
    float* partials   = (float*)(ws + 73924608);                   //  2,048,000 B
    float* zt         = (float*)(ws + 78020608);                   //     16,384 B
    float* logp       = (float*)(ws + 78036992);                   //     16,384 B

    cvt_i8_kernel<<<dim3(64000), 256, 0, stream>>>(W, Wq, 127.0f / 0.125f);
    cvt_i8_kernel<<<dim3(8192), 256, 0, stream>>>(X, Xq, 127.0f / 6.0f);
    zt_kernel<<<dim3(1024), 256, 0, stream>>>(X, W, bias, target, zt);
    gemm_lse_kernel<<<dim3(NMT * NVT), 1024, 0, stream>>>(Xq, Wq, bias, partials);
    lse_kernel<<<dim3(16), 256, 0, stream>>>(partials, zt, logp);
    loss_kernel<<<dim3(1), 512, 0, stream>>>(logp, target, out);
}